// Round 7
// baseline (7859.267 us; speedup 1.0000x reference)
//
#include <hip/hip_runtime.h>
#include <math.h>

#define N 512
#define NITERS 100
#define SC 10.0f

// round-to-nearest-even fp32 -> bf16 pair packed into one uint
__device__ __forceinline__ unsigned int pack_bf16(float a, float b) {
    unsigned int ua = __float_as_uint(a);
    unsigned int ub = __float_as_uint(b);
    ua = (ua + 0x7fffu + ((ua >> 16) & 1u)) >> 16;
    ub = (ub + 0x7fffu + ((ub >> 16) & 1u)) >> 16;
    return ua | (ub << 16);
}

// s = sum over this lane's 8 bf16 elements of K-row times w
__device__ __forceinline__ float rowdot(uint4 q, float4 w0, float4 w1) {
    float f0 = __uint_as_float(q.x << 16);
    float f1 = __uint_as_float(q.x & 0xffff0000u);
    float f2 = __uint_as_float(q.y << 16);
    float f3 = __uint_as_float(q.y & 0xffff0000u);
    float f4 = __uint_as_float(q.z << 16);
    float f5 = __uint_as_float(q.z & 0xffff0000u);
    float f6 = __uint_as_float(q.w << 16);
    float f7 = __uint_as_float(q.w & 0xffff0000u);
    float sa = f0 * w0.x;
    sa = fmaf(f2, w0.z, sa);
    sa = fmaf(f4, w1.x, sa);
    sa = fmaf(f6, w1.z, sa);
    float sb = f1 * w0.y;
    sb = fmaf(f3, w0.w, sb);
    sb = fmaf(f5, w1.y, sb);
    sb = fmaf(f7, w1.w, sb);
    return sa + sb;
}

// t_j += K_ij * r  for this lane's 8 columns
__device__ __forceinline__ void tacc(uint4 q, float r,
        float& t0, float& t1, float& t2, float& t3,
        float& t4, float& t5, float& t6, float& t7) {
    t0 = fmaf(__uint_as_float(q.x << 16),         r, t0);
    t1 = fmaf(__uint_as_float(q.x & 0xffff0000u), r, t1);
    t2 = fmaf(__uint_as_float(q.y << 16),         r, t2);
    t3 = fmaf(__uint_as_float(q.y & 0xffff0000u), r, t3);
    t4 = fmaf(__uint_as_float(q.z << 16),         r, t4);
    t5 = fmaf(__uint_as_float(q.z & 0xffff0000u), r, t5);
    t6 = fmaf(__uint_as_float(q.w << 16),         r, t6);
    t7 = fmaf(__uint_as_float(q.w & 0xffff0000u), r, t7);
}

// NO ARRAYS for batch state: rounds 5/6 used uint4 cur[8]/nxt[8] and the
// backend left the allocas in scratch (VGPR stuck at 64, 9.5 GB spill
// traffic, 3.6x slowdown). Named scalars only.
#define LD(p, k) (((const uint4*)((p) + (size_t)(k) * RS))[lane])
#define PRE8(S, p) \
    S##0 = LD(p, 0); S##1 = LD(p, 1); S##2 = LD(p, 2); S##3 = LD(p, 3); \
    S##4 = LD(p, 4); S##5 = LD(p, 5); S##6 = LD(p, 6); S##7 = LD(p, 7);

#define BATCH8(S, bidx) { \
    float s0 = rowdot(S##0, w0, w1), s1 = rowdot(S##1, w0, w1); \
    float s2 = rowdot(S##2, w0, w1), s3 = rowdot(S##3, w0, w1); \
    float s4 = rowdot(S##4, w0, w1), s5 = rowdot(S##5, w0, w1); \
    float s6 = rowdot(S##6, w0, w1), s7 = rowdot(S##7, w0, w1); \
    _Pragma("unroll") \
    for (int o = 32; o > 0; o >>= 1) { \
        s0 += __shfl_xor(s0, o, 64); s1 += __shfl_xor(s1, o, 64); \
        s2 += __shfl_xor(s2, o, 64); s3 += __shfl_xor(s3, o, 64); \
        s4 += __shfl_xor(s4, o, 64); s5 += __shfl_xor(s5, o, 64); \
        s6 += __shfl_xor(s6, o, 64); s7 += __shfl_xor(s7, o, 64); \
    } \
    if (last && lane == 0) { \
        lnS_s[wave + 16 * (8 * (bidx) + 0)] = __logf(s0); \
        lnS_s[wave + 16 * (8 * (bidx) + 1)] = __logf(s1); \
        lnS_s[wave + 16 * (8 * (bidx) + 2)] = __logf(s2); \
        lnS_s[wave + 16 * (8 * (bidx) + 3)] = __logf(s3); \
        lnS_s[wave + 16 * (8 * (bidx) + 4)] = __logf(s4); \
        lnS_s[wave + 16 * (8 * (bidx) + 5)] = __logf(s5); \
        lnS_s[wave + 16 * (8 * (bidx) + 6)] = __logf(s6); \
        lnS_s[wave + 16 * (8 * (bidx) + 7)] = __logf(s7); \
    } \
    s0 = __builtin_amdgcn_rcpf(s0); s1 = __builtin_amdgcn_rcpf(s1); \
    s2 = __builtin_amdgcn_rcpf(s2); s3 = __builtin_amdgcn_rcpf(s3); \
    s4 = __builtin_amdgcn_rcpf(s4); s5 = __builtin_amdgcn_rcpf(s5); \
    s6 = __builtin_amdgcn_rcpf(s6); s7 = __builtin_amdgcn_rcpf(s7); \
    tacc(S##0, s0, t0, t1, t2, t3, t4, t5, t6, t7); \
    tacc(S##1, s1, t0, t1, t2, t3, t4, t5, t6, t7); \
    tacc(S##2, s2, t0, t1, t2, t3, t4, t5, t6, t7); \
    tacc(S##3, s3, t0, t1, t2, t3, t4, t5, t6, t7); \
    tacc(S##4, s4, t0, t1, t2, t3, t4, t5, t6, t7); \
    tacc(S##5, s5, t0, t1, t2, t3, t4, t5, t6, t7); \
    tacc(S##6, s6, t0, t1, t2, t3, t4, t5, t6, t7); \
    tacc(S##7, s7, t0, t1, t2, t3, t4, t5, t6, t7); \
}

// One block (1024 thr, 16 waves) per matrix. Multiplicative Sinkhorn on a
// precomputed bf16 kernel K' = exp(A*SC - rowmax_i) stored in this block's
// own d_out region:
//   s_i = sum_j K'_ij w_j ; r_i = 1/s_i ; t_j = sum_i K'_ij r_i ; w_j = 1/t_j
// 8-row batches as named scalars: 8-16 loads in flight, 8 interleaved
// butterfly chains, K' read once per iteration (t-pass reuses registers).
__global__ __launch_bounds__(1024, 4)
void sinkhorn_ssa(const float* __restrict__ X, float* __restrict__ P) {
    __shared__ float w_s[N];        // column scaling w
    __shared__ float m_s[N];        // rowmax of A*SC
    __shared__ float lnS_s[N];      // ln(row sum) at final row pass
    __shared__ float c_lds[16 * N]; // per-wave t partials

    const int tid  = threadIdx.x;
    const int lane = tid & 63;
    const int wave = tid >> 6;          // 0..15

    const size_t base = (size_t)blockIdx.x * N * N;
    const float* __restrict__ A   = X + base;
    float*       __restrict__ out = P + base;
    unsigned short* __restrict__ Kb = (unsigned short*)(P + base);  // 512 KB own region

    if (tid < N) w_s[tid] = 1.0f;

    // ---- precompute K' = exp(A*SC - rowmax) in bf16; rowmax -> m_s ----
    #pragma unroll 1
    for (int r = wave; r < N; r += 16) {
        const float4* rowp = (const float4*)(A + (size_t)r * N);
        float4 a0 = rowp[lane];          // cols 4L..4L+3
        float4 a1 = rowp[lane + 64];     // cols 256+4L..
        float x0 = a0.x * SC, x1 = a0.y * SC, x2 = a0.z * SC, x3 = a0.w * SC;
        float x4 = a1.x * SC, x5 = a1.y * SC, x6 = a1.z * SC, x7 = a1.w * SC;
        float mx = fmaxf(fmaxf(fmaxf(x0, x1), fmaxf(x2, x3)),
                         fmaxf(fmaxf(x4, x5), fmaxf(x6, x7)));
        #pragma unroll
        for (int o = 32; o > 0; o >>= 1) mx = fmaxf(mx, __shfl_xor(mx, o, 64));
        uint2 p0, p1;
        p0.x = pack_bf16(__expf(x0 - mx), __expf(x1 - mx));
        p0.y = pack_bf16(__expf(x2 - mx), __expf(x3 - mx));
        p1.x = pack_bf16(__expf(x4 - mx), __expf(x5 - mx));
        p1.y = pack_bf16(__expf(x6 - mx), __expf(x7 - mx));
        uint2* krow = (uint2*)(Kb + (size_t)r * N);
        krow[lane]      = p0;
        krow[lane + 64] = p1;
        if (lane == 0) m_s[r] = mx;
    }
    __threadfence();
    __syncthreads();

    // ---- 100 iterations ----
    const size_t RS = (size_t)16 * N;   // ushorts between this wave's rows
    for (int it = 0; it < NITERS; ++it) {
        const bool last = (it == NITERS - 1);
        const float4 w0 = *(const float4*)(w_s + 8 * lane);      // cols 8L..8L+3
        const float4 w1 = *(const float4*)(w_s + 8 * lane + 4);  // cols 8L+4..8L+7
        float t0 = 0.f, t1 = 0.f, t2 = 0.f, t3 = 0.f,
              t4 = 0.f, t5 = 0.f, t6 = 0.f, t7 = 0.f;

        const unsigned short* kp = Kb + (size_t)wave * N;
        uint4 a0, a1, a2, a3, a4, a5, a6, a7;
        uint4 b0, b1, b2, b3, b4, b5, b6, b7;

        PRE8(a, kp)              // rows m = 0..7   (r = wave + 16*m)
        PRE8(b, kp + 8 * RS)     // rows m = 8..15
        BATCH8(a, 0)
        PRE8(a, kp + 16 * RS)    // rows m = 16..23
        BATCH8(b, 1)
        PRE8(b, kp + 24 * RS)    // rows m = 24..31
        BATCH8(a, 2)
        BATCH8(b, 3)

        // cross-wave t reduction
        *(float4*)(c_lds + wave * N + 8 * lane)     = make_float4(t0, t1, t2, t3);
        *(float4*)(c_lds + wave * N + 8 * lane + 4) = make_float4(t4, t5, t6, t7);
        __syncthreads();
        if (tid < N) {
            float cs = 0.f;
            #pragma unroll
            for (int w = 0; w < 16; ++w) cs += c_lds[w * N + tid];
            w_s[tid] = __builtin_amdgcn_rcpf(fmaxf(cs, 1e-38f));
        }
        __syncthreads();
    }

    // ---- epilogue: P = exp(A*SC - m_i - lnS_i + ln w_j) from fp32 A ----
    float* g_s  = c_lds;        // ln w  [N]
    float* rt_s = c_lds + N;    // -(m + lnS) [N]
    if (tid < N) {
        g_s[tid]  = __logf(w_s[tid]);
        rt_s[tid] = -(m_s[tid] + lnS_s[tid]);
    }
    __syncthreads();

    #pragma unroll 1
    for (int r = wave; r < N; r += 16) {
        const float rt = rt_s[r];
        const float4* rowp = (const float4*)(A + (size_t)r * N);
        float4 a0 = rowp[lane];
        float4 a1 = rowp[lane + 64];
        float4 g0 = *(const float4*)(g_s + 4 * lane);
        float4 g1 = *(const float4*)(g_s + 256 + 4 * lane);
        float4 o0, o1;
        o0.x = __expf(fmaf(a0.x, SC, rt) + g0.x);
        o0.y = __expf(fmaf(a0.y, SC, rt) + g0.y);
        o0.z = __expf(fmaf(a0.z, SC, rt) + g0.z);
        o0.w = __expf(fmaf(a0.w, SC, rt) + g0.w);
        o1.x = __expf(fmaf(a1.x, SC, rt) + g1.x);
        o1.y = __expf(fmaf(a1.y, SC, rt) + g1.y);
        o1.z = __expf(fmaf(a1.z, SC, rt) + g1.z);
        o1.w = __expf(fmaf(a1.w, SC, rt) + g1.w);
        float4* outp = (float4*)(out + (size_t)r * N);
        outp[lane]      = o0;
        outp[lane + 64] = o1;
    }
}

extern "C" void kernel_launch(void* const* d_in, const int* in_sizes, int n_in,
                              void* d_out, int out_size, void* d_ws, size_t ws_size,
                              hipStream_t stream) {
    const float* X = (const float*)d_in[0];
    float* P = (float*)d_out;
    const int batch = in_sizes[0] / (N * N);   // 128
    hipLaunchKernelGGL(sinkhorn_ssa, dim3(batch), dim3(1024), 0, stream, X, P);
}

// Round 8
// 7753.577 us; speedup vs baseline: 1.0136x; 1.0136x over previous
//
#include <hip/hip_runtime.h>
#include <math.h>

#define N 512
#define NITERS 100
#define SC 10.0f

// round-to-nearest-even fp32 -> bf16 pair packed into one uint
__device__ __forceinline__ unsigned int pack_bf16(float a, float b) {
    unsigned int ua = __float_as_uint(a);
    unsigned int ub = __float_as_uint(b);
    ua = (ua + 0x7fffu + ((ua >> 16) & 1u)) >> 16;
    ub = (ub + 0x7fffu + ((ub >> 16) & 1u)) >> 16;
    return ua | (ub << 16);
}

// s = sum over this lane's 8 bf16 elements of K-row times w
__device__ __forceinline__ float rowdot(uint4 q, float4 w0, float4 w1) {
    float f0 = __uint_as_float(q.x << 16);
    float f1 = __uint_as_float(q.x & 0xffff0000u);
    float f2 = __uint_as_float(q.y << 16);
    float f3 = __uint_as_float(q.y & 0xffff0000u);
    float f4 = __uint_as_float(q.z << 16);
    float f5 = __uint_as_float(q.z & 0xffff0000u);
    float f6 = __uint_as_float(q.w << 16);
    float f7 = __uint_as_float(q.w & 0xffff0000u);
    float sa = f0 * w0.x;
    sa = fmaf(f2, w0.z, sa);
    sa = fmaf(f4, w1.x, sa);
    sa = fmaf(f6, w1.z, sa);
    float sb = f1 * w0.y;
    sb = fmaf(f3, w0.w, sb);
    sb = fmaf(f5, w1.y, sb);
    sb = fmaf(f7, w1.w, sb);
    return sa + sb;
}

// t_j += K_ij * r  for this lane's 8 columns
__device__ __forceinline__ void tacc(uint4 q, float r,
        float& t0, float& t1, float& t2, float& t3,
        float& t4, float& t5, float& t6, float& t7) {
    t0 = fmaf(__uint_as_float(q.x << 16),         r, t0);
    t1 = fmaf(__uint_as_float(q.x & 0xffff0000u), r, t1);
    t2 = fmaf(__uint_as_float(q.y << 16),         r, t2);
    t3 = fmaf(__uint_as_float(q.y & 0xffff0000u), r, t3);
    t4 = fmaf(__uint_as_float(q.z << 16),         r, t4);
    t5 = fmaf(__uint_as_float(q.z & 0xffff0000u), r, t5);
    t6 = fmaf(__uint_as_float(q.w << 16),         r, t6);
    t7 = fmaf(__uint_as_float(q.w & 0xffff0000u), r, t7);
}

#define LD(p, k) (((const uint4*)((p) + (size_t)(k) * RS))[lane])
#define PRE8(S, p) \
    S##0 = LD(p, 0); S##1 = LD(p, 1); S##2 = LD(p, 2); S##3 = LD(p, 3); \
    S##4 = LD(p, 4); S##5 = LD(p, 5); S##6 = LD(p, 6); S##7 = LD(p, 7);

#define BATCH8(S, bidx) { \
    float s0 = rowdot(S##0, w0, w1), s1 = rowdot(S##1, w0, w1); \
    float s2 = rowdot(S##2, w0, w1), s3 = rowdot(S##3, w0, w1); \
    float s4 = rowdot(S##4, w0, w1), s5 = rowdot(S##5, w0, w1); \
    float s6 = rowdot(S##6, w0, w1), s7 = rowdot(S##7, w0, w1); \
    _Pragma("unroll") \
    for (int o = 32; o > 0; o >>= 1) { \
        s0 += __shfl_xor(s0, o, 64); s1 += __shfl_xor(s1, o, 64); \
        s2 += __shfl_xor(s2, o, 64); s3 += __shfl_xor(s3, o, 64); \
        s4 += __shfl_xor(s4, o, 64); s5 += __shfl_xor(s5, o, 64); \
        s6 += __shfl_xor(s6, o, 64); s7 += __shfl_xor(s7, o, 64); \
    } \
    if (last && lane == 0) { \
        lnS_s[wave + 16 * (8 * (bidx) + 0)] = __logf(s0); \
        lnS_s[wave + 16 * (8 * (bidx) + 1)] = __logf(s1); \
        lnS_s[wave + 16 * (8 * (bidx) + 2)] = __logf(s2); \
        lnS_s[wave + 16 * (8 * (bidx) + 3)] = __logf(s3); \
        lnS_s[wave + 16 * (8 * (bidx) + 4)] = __logf(s4); \
        lnS_s[wave + 16 * (8 * (bidx) + 5)] = __logf(s5); \
        lnS_s[wave + 16 * (8 * (bidx) + 6)] = __logf(s6); \
        lnS_s[wave + 16 * (8 * (bidx) + 7)] = __logf(s7); \
    } \
    s0 = __builtin_amdgcn_rcpf(s0); s1 = __builtin_amdgcn_rcpf(s1); \
    s2 = __builtin_amdgcn_rcpf(s2); s3 = __builtin_amdgcn_rcpf(s3); \
    s4 = __builtin_amdgcn_rcpf(s4); s5 = __builtin_amdgcn_rcpf(s5); \
    s6 = __builtin_amdgcn_rcpf(s6); s7 = __builtin_amdgcn_rcpf(s7); \
    tacc(S##0, s0, t0, t1, t2, t3, t4, t5, t6, t7); \
    tacc(S##1, s1, t0, t1, t2, t3, t4, t5, t6, t7); \
    tacc(S##2, s2, t0, t1, t2, t3, t4, t5, t6, t7); \
    tacc(S##3, s3, t0, t1, t2, t3, t4, t5, t6, t7); \
    tacc(S##4, s4, t0, t1, t2, t3, t4, t5, t6, t7); \
    tacc(S##5, s5, t0, t1, t2, t3, t4, t5, t6, t7); \
    tacc(S##6, s6, t0, t1, t2, t3, t4, t5, t6, t7); \
    tacc(S##7, s7, t0, t1, t2, t3, t4, t5, t6, t7); \
}

// One block (1024 thr, 16 waves) per matrix. Multiplicative Sinkhorn on a
// precomputed bf16 kernel K' = exp(A*SC - rowmax_i) stored in this block's
// own d_out region:
//   s_i = sum_j K'_ij w_j ; r_i = 1/s_i ; t_j = sum_i K'_ij r_i ; w_j = 1/t_j
//
// OCCUPANCY DIRECTIVE (rounds 5-7 lesson): __launch_bounds__(B, w) only sets
// the MINIMUM waves/EU (VGPR upper bound); with 38.9 KB LDS the backend sees
// 2 blocks/CU fit, targets 8 waves/EU, caps VGPRs at 64, and spills the
// ~95-reg working set (9.5 GB scratch traffic, 3.6x slowdown; VGPR_Count=64
// in rocprof is the tell). amdgpu_waves_per_eu(4,4) pins min AND max ->
// 128-VGPR budget. If VGPR still reads 64: pad LDS >80KB instead.
__global__ __launch_bounds__(1024) __attribute__((amdgpu_waves_per_eu(4, 4)))
void sinkhorn_ssa(const float* __restrict__ X, float* __restrict__ P) {
    __shared__ float w_s[N];        // column scaling w
    __shared__ float m_s[N];        // rowmax of A*SC
    __shared__ float lnS_s[N];      // ln(row sum) at final row pass
    __shared__ float c_lds[16 * N]; // per-wave t partials

    const int tid  = threadIdx.x;
    const int lane = tid & 63;
    const int wave = tid >> 6;          // 0..15

    const size_t base = (size_t)blockIdx.x * N * N;
    const float* __restrict__ A   = X + base;
    float*       __restrict__ out = P + base;
    unsigned short* __restrict__ Kb = (unsigned short*)(P + base);  // 512 KB own region

    if (tid < N) w_s[tid] = 1.0f;

    // ---- precompute K' = exp(A*SC - rowmax) in bf16; rowmax -> m_s ----
    #pragma unroll 1
    for (int r = wave; r < N; r += 16) {
        const float4* rowp = (const float4*)(A + (size_t)r * N);
        float4 a0 = rowp[lane];          // cols 4L..4L+3
        float4 a1 = rowp[lane + 64];     // cols 256+4L..
        float x0 = a0.x * SC, x1 = a0.y * SC, x2 = a0.z * SC, x3 = a0.w * SC;
        float x4 = a1.x * SC, x5 = a1.y * SC, x6 = a1.z * SC, x7 = a1.w * SC;
        float mx = fmaxf(fmaxf(fmaxf(x0, x1), fmaxf(x2, x3)),
                         fmaxf(fmaxf(x4, x5), fmaxf(x6, x7)));
        #pragma unroll
        for (int o = 32; o > 0; o >>= 1) mx = fmaxf(mx, __shfl_xor(mx, o, 64));
        uint2 p0, p1;
        p0.x = pack_bf16(__expf(x0 - mx), __expf(x1 - mx));
        p0.y = pack_bf16(__expf(x2 - mx), __expf(x3 - mx));
        p1.x = pack_bf16(__expf(x4 - mx), __expf(x5 - mx));
        p1.y = pack_bf16(__expf(x6 - mx), __expf(x7 - mx));
        uint2* krow = (uint2*)(Kb + (size_t)r * N);
        krow[lane]      = p0;
        krow[lane + 64] = p1;
        if (lane == 0) m_s[r] = mx;
    }
    __threadfence();
    __syncthreads();

    // ---- 100 iterations ----
    const size_t RS = (size_t)16 * N;   // ushorts between this wave's rows
    for (int it = 0; it < NITERS; ++it) {
        const bool last = (it == NITERS - 1);
        const float4 w0 = *(const float4*)(w_s + 8 * lane);      // cols 8L..8L+3
        const float4 w1 = *(const float4*)(w_s + 8 * lane + 4);  // cols 8L+4..8L+7
        float t0 = 0.f, t1 = 0.f, t2 = 0.f, t3 = 0.f,
              t4 = 0.f, t5 = 0.f, t6 = 0.f, t7 = 0.f;

        const unsigned short* kp = Kb + (size_t)wave * N;
        uint4 a0, a1, a2, a3, a4, a5, a6, a7;
        uint4 b0, b1, b2, b3, b4, b5, b6, b7;

        PRE8(a, kp)              // rows m = 0..7   (r = wave + 16*m)
        PRE8(b, kp + 8 * RS)     // rows m = 8..15
        BATCH8(a, 0)
        PRE8(a, kp + 16 * RS)    // rows m = 16..23
        BATCH8(b, 1)
        PRE8(b, kp + 24 * RS)    // rows m = 24..31
        BATCH8(a, 2)
        BATCH8(b, 3)

        // cross-wave t reduction
        *(float4*)(c_lds + wave * N + 8 * lane)     = make_float4(t0, t1, t2, t3);
        *(float4*)(c_lds + wave * N + 8 * lane + 4) = make_float4(t4, t5, t6, t7);
        __syncthreads();
        if (tid < N) {
            float cs = 0.f;
            #pragma unroll
            for (int w = 0; w < 16; ++w) cs += c_lds[w * N + tid];
            w_s[tid] = __builtin_amdgcn_rcpf(fmaxf(cs, 1e-38f));
        }
        __syncthreads();
    }

    // ---- epilogue: P = exp(A*SC - m_i - lnS_i + ln w_j) from fp32 A ----
    float* g_s  = c_lds;        // ln w  [N]
    float* rt_s = c_lds + N;    // -(m + lnS) [N]
    if (tid < N) {
        g_s[tid]  = __logf(w_s[tid]);
        rt_s[tid] = -(m_s[tid] + lnS_s[tid]);
    }
    __syncthreads();

    #pragma unroll 1
    for (int r = wave; r < N; r += 16) {
        const float rt = rt_s[r];
        const float4* rowp = (const float4*)(A + (size_t)r * N);
        float4 a0 = rowp[lane];
        float4 a1 = rowp[lane + 64];
        float4 g0 = *(const float4*)(g_s + 4 * lane);
        float4 g1 = *(const float4*)(g_s + 256 + 4 * lane);
        float4 o0, o1;
        o0.x = __expf(fmaf(a0.x, SC, rt) + g0.x);
        o0.y = __expf(fmaf(a0.y, SC, rt) + g0.y);
        o0.z = __expf(fmaf(a0.z, SC, rt) + g0.z);
        o0.w = __expf(fmaf(a0.w, SC, rt) + g0.w);
        o1.x = __expf(fmaf(a1.x, SC, rt) + g1.x);
        o1.y = __expf(fmaf(a1.y, SC, rt) + g1.y);
        o1.z = __expf(fmaf(a1.z, SC, rt) + g1.z);
        o1.w = __expf(fmaf(a1.w, SC, rt) + g1.w);
        float4* outp = (float4*)(out + (size_t)r * N);
        outp[lane]      = o0;
        outp[lane + 64] = o1;
    }
}

extern "C" void kernel_launch(void* const* d_in, const int* in_sizes, int n_in,
                              void* d_out, int out_size, void* d_ws, size_t ws_size,
                              hipStream_t stream) {
    const float* X = (const float*)d_in[0];
    float* P = (float*)d_out;
    const int batch = in_sizes[0] / (N * N);   // 128
    hipLaunchKernelGGL(sinkhorn_ssa, dim3(batch), dim3(1024), 0, stream, X, P);
}

// Round 9
// 2517.307 us; speedup vs baseline: 3.1221x; 3.0801x over previous
//
#include <hip/hip_runtime.h>
#include <math.h>

#define N 512
#define NITERS 100
#define SC 10.0f

// round-to-nearest-even fp32 -> bf16 pair packed into one uint
__device__ __forceinline__ unsigned int pack_bf16(float a, float b) {
    unsigned int ua = __float_as_uint(a);
    unsigned int ub = __float_as_uint(b);
    ua = (ua + 0x7fffu + ((ua >> 16) & 1u)) >> 16;
    ub = (ub + 0x7fffu + ((ub >> 16) & 1u)) >> 16;
    return ua | (ub << 16);
}

// unpack 8 bf16 from a uint4, fma each by scalar W into 8 named accumulators
#define UPFMA8(Q, W, z0,z1,z2,z3,z4,z5,z6,z7) \
    z0 = fmaf(__uint_as_float((Q).x << 16),         (W), z0); \
    z1 = fmaf(__uint_as_float((Q).x & 0xffff0000u), (W), z1); \
    z2 = fmaf(__uint_as_float((Q).y << 16),         (W), z2); \
    z3 = fmaf(__uint_as_float((Q).y & 0xffff0000u), (W), z3); \
    z4 = fmaf(__uint_as_float((Q).z << 16),         (W), z4); \
    z5 = fmaf(__uint_as_float((Q).z & 0xffff0000u), (W), z5); \
    z6 = fmaf(__uint_as_float((Q).w << 16),         (W), z6); \
    z7 = fmaf(__uint_as_float((Q).w & 0xffff0000u), (W), z7);

// One block (1024 thr, 16 waves) per matrix. Multiplicative Sinkhorn on a
// bf16 kernel stored TWICE (row-major K and transposed Kt) in this block's
// own 1MB d_out region. Both passes are scaled-accumulates with NO cross-lane
// reduction and <64 VGPR live state (rounds 5-8: compiler hard-caps this
// kernel at 64 VGPRs; ~100-reg designs spill 9.3GB to scratch. Design for 64.)
//   pass A: s_i += K[i][j] * w_j   (read Kt rows, lane owns 8 i's)
//   pass B: t_j += K[i][j] * r_i   (read K  rows, lane owns 8 j's)
//   r = 1/s, w = 1/t; cross-wave combine via one LDS reduce per pass.
__global__ __launch_bounds__(1024)
void sinkhorn_2layout(const float* __restrict__ X, float* __restrict__ P) {
    __shared__ float w_s[N], r_s[N], m_s[N], lnS_s[N];
    __shared__ float c_lds[16 * N];               // per-wave partials
    __shared__ unsigned int slab_u[16 * 256];     // 16 rows x 512 bf16 (transpose stage)

    const int tid  = threadIdx.x;
    const int lane = tid & 63;
    const int wave = tid >> 6;          // 0..15

    const size_t base = (size_t)blockIdx.x * N * N;
    const float* __restrict__ A   = X + base;
    float*       __restrict__ out = P + base;
    unsigned short* Kb = (unsigned short*)(P + base);      // [0, 512KB): K row-major
    unsigned short* Kt = Kb + (size_t)N * N;               // [512KB, 1MB): K transposed

    if (tid < N) w_s[tid] = 1.0f;

    // ---- pass 0: K = exp(A*SC - rowmax) bf16, row-major + transposed ----
    for (int b = 0; b < 32; ++b) {
        const int r = 16 * b + wave;
        const float4* rowp = (const float4*)(A + (size_t)r * N);
        float4 a0 = rowp[lane];          // cols 4L..4L+3
        float4 a1 = rowp[lane + 64];     // cols 256+4L..
        float x0 = a0.x*SC, x1 = a0.y*SC, x2 = a0.z*SC, x3 = a0.w*SC;
        float x4 = a1.x*SC, x5 = a1.y*SC, x6 = a1.z*SC, x7 = a1.w*SC;
        float mx = fmaxf(fmaxf(fmaxf(x0,x1), fmaxf(x2,x3)),
                         fmaxf(fmaxf(x4,x5), fmaxf(x6,x7)));
        #pragma unroll
        for (int o = 32; o > 0; o >>= 1) mx = fmaxf(mx, __shfl_xor(mx, o, 64));
        uint2 p0, p1;
        p0.x = pack_bf16(__expf(x0 - mx), __expf(x1 - mx));
        p0.y = pack_bf16(__expf(x2 - mx), __expf(x3 - mx));
        p1.x = pack_bf16(__expf(x4 - mx), __expf(x5 - mx));
        p1.y = pack_bf16(__expf(x6 - mx), __expf(x7 - mx));
        uint2* krow = (uint2*)(Kb + (size_t)r * N);
        krow[lane]      = p0;            // cols 4L..4L+3
        krow[lane + 64] = p1;            // cols 256+4L..
        if (lane == 0) m_s[r] = mx;
        // stage this 16-row slab in LDS for the transposed copy
        *(uint2*)(slab_u + wave * 256 + 2 * lane)       = p0;
        *(uint2*)(slab_u + wave * 256 + 128 + 2 * lane) = p1;
        __syncthreads();
        {   // thread -> (column c, row-half h): write Kt[c][16b+8h .. +7]
            const int c = tid >> 1, h = tid & 1;
            const unsigned short* sl = (const unsigned short*)slab_u;
            unsigned short v0 = sl[(8*h+0)*N + c];
            unsigned short v1 = sl[(8*h+1)*N + c];
            unsigned short v2 = sl[(8*h+2)*N + c];
            unsigned short v3 = sl[(8*h+3)*N + c];
            unsigned short v4 = sl[(8*h+4)*N + c];
            unsigned short v5 = sl[(8*h+5)*N + c];
            unsigned short v6 = sl[(8*h+6)*N + c];
            unsigned short v7 = sl[(8*h+7)*N + c];
            uint4 q;
            q.x = v0 | ((unsigned)v1 << 16);
            q.y = v2 | ((unsigned)v3 << 16);
            q.z = v4 | ((unsigned)v5 << 16);
            q.w = v6 | ((unsigned)v7 << 16);
            *(uint4*)(Kt + (size_t)c * N + 16 * b + 8 * h) = q;
        }
        __syncthreads();
    }
    __threadfence();     // own global K/Kt writes visible before re-reads
    __syncthreads();

    const uint4* KtV = (const uint4*)Kt;   // row j = 64 uint4
    const uint4* KbV = (const uint4*)Kb;   // row i = 64 uint4

    // ---- 100 iterations, no cross-lane ops ----
    for (int it = 0; it < NITERS; ++it) {
        const bool last = (it == NITERS - 1);

        // pass A: wave owns j in [32w, 32w+32); lane owns i = 8L..8L+7
        {
            float s0=0.f,s1=0.f,s2=0.f,s3=0.f,s4=0.f,s5=0.f,s6=0.f,s7=0.f;
            const int J = 32 * wave;
            const uint4* p = KtV + (size_t)J * 64 + lane;
            uint4 c0 = p[0], c1 = p[64], c2 = p[128], c3 = p[192];
            #pragma unroll
            for (int g = 0; g < 8; ++g) {
                uint4 n0, n1, n2, n3;
                if (g < 7) {
                    const uint4* q = p + (size_t)(g + 1) * 256;
                    n0 = q[0]; n1 = q[64]; n2 = q[128]; n3 = q[192];
                }
                const float wa = w_s[J + 4*g + 0];
                const float wb = w_s[J + 4*g + 1];
                const float wc = w_s[J + 4*g + 2];
                const float wd = w_s[J + 4*g + 3];
                UPFMA8(c0, wa, s0,s1,s2,s3,s4,s5,s6,s7)
                UPFMA8(c1, wb, s0,s1,s2,s3,s4,s5,s6,s7)
                UPFMA8(c2, wc, s0,s1,s2,s3,s4,s5,s6,s7)
                UPFMA8(c3, wd, s0,s1,s2,s3,s4,s5,s6,s7)
                if (g < 7) { c0 = n0; c1 = n1; c2 = n2; c3 = n3; }
            }
            *(float4*)(c_lds + wave * N + 8 * lane)     = make_float4(s0,s1,s2,s3);
            *(float4*)(c_lds + wave * N + 8 * lane + 4) = make_float4(s4,s5,s6,s7);
        }
        __syncthreads();
        if (tid < N) {
            float cs = 0.f;
            #pragma unroll
            for (int w = 0; w < 16; ++w) cs += c_lds[w * N + tid];
            cs = fmaxf(cs, 1e-38f);
            if (last) lnS_s[tid] = __logf(cs);
            r_s[tid] = __builtin_amdgcn_rcpf(cs);
        }
        __syncthreads();

        // pass B: wave owns i in [32w, 32w+32); lane owns j = 8L..8L+7
        {
            float t0=0.f,t1=0.f,t2=0.f,t3=0.f,t4=0.f,t5=0.f,t6=0.f,t7=0.f;
            const int I = 32 * wave;
            const uint4* p = KbV + (size_t)I * 64 + lane;
            uint4 c0 = p[0], c1 = p[64], c2 = p[128], c3 = p[192];
            #pragma unroll
            for (int g = 0; g < 8; ++g) {
                uint4 n0, n1, n2, n3;
                if (g < 7) {
                    const uint4* q = p + (size_t)(g + 1) * 256;
                    n0 = q[0]; n1 = q[64]; n2 = q[128]; n3 = q[192];
                }
                const float ra = r_s[I + 4*g + 0];
                const float rb = r_s[I + 4*g + 1];
                const float rc = r_s[I + 4*g + 2];
                const float rd = r_s[I + 4*g + 3];
                UPFMA8(c0, ra, t0,t1,t2,t3,t4,t5,t6,t7)
                UPFMA8(c1, rb, t0,t1,t2,t3,t4,t5,t6,t7)
                UPFMA8(c2, rc, t0,t1,t2,t3,t4,t5,t6,t7)
                UPFMA8(c3, rd, t0,t1,t2,t3,t4,t5,t6,t7)
                if (g < 7) { c0 = n0; c1 = n1; c2 = n2; c3 = n3; }
            }
            *(float4*)(c_lds + wave * N + 8 * lane)     = make_float4(t0,t1,t2,t3);
            *(float4*)(c_lds + wave * N + 8 * lane + 4) = make_float4(t4,t5,t6,t7);
        }
        __syncthreads();
        if (tid < N) {
            float ct = 0.f;
            #pragma unroll
            for (int w = 0; w < 16; ++w) ct += c_lds[w * N + tid];
            w_s[tid] = __builtin_amdgcn_rcpf(fmaxf(ct, 1e-38f));
        }
        __syncthreads();
    }

    // ---- epilogue: P = exp(A*SC - m_i - lnS_i + ln w_j) from fp32 A ----
    float* g_s  = c_lds;        // ln w  [N]
    float* rt_s = c_lds + N;    // -(m + lnS) [N]
    if (tid < N) {
        g_s[tid]  = __logf(w_s[tid]);
        rt_s[tid] = -(m_s[tid] + lnS_s[tid]);
    }
    __syncthreads();

    #pragma unroll 1
    for (int r = wave; r < N; r += 16) {
        const float rt = rt_s[r];
        const float4* rowp = (const float4*)(A + (size_t)r * N);
        float4 a0 = rowp[lane];
        float4 a1 = rowp[lane + 64];
        float4 g0 = *(const float4*)(g_s + 4 * lane);
        float4 g1 = *(const float4*)(g_s + 256 + 4 * lane);
        float4 o0, o1;
        o0.x = __expf(fmaf(a0.x, SC, rt) + g0.x);
        o0.y = __expf(fmaf(a0.y, SC, rt) + g0.y);
        o0.z = __expf(fmaf(a0.z, SC, rt) + g0.z);
        o0.w = __expf(fmaf(a0.w, SC, rt) + g0.w);
        o1.x = __expf(fmaf(a1.x, SC, rt) + g1.x);
        o1.y = __expf(fmaf(a1.y, SC, rt) + g1.y);
        o1.z = __expf(fmaf(a1.z, SC, rt) + g1.z);
        o1.w = __expf(fmaf(a1.w, SC, rt) + g1.w);
        float4* outp = (float4*)(out + (size_t)r * N);
        outp[lane]      = o0;
        outp[lane + 64] = o1;
    }
}

extern "C" void kernel_launch(void* const* d_in, const int* in_sizes, int n_in,
                              void* d_out, int out_size, void* d_ws, size_t ws_size,
                              hipStream_t stream) {
    const float* X = (const float*)d_in[0];
    float* P = (float*)d_out;
    const int batch = in_sizes[0] / (N * N);   // 128
    hipLaunchKernelGGL(sinkhorn_2layout, dim3(batch), dim3(1024), 0, stream, X, P);
}